// Round 11
// baseline (308.438 us; speedup 1.0000x reference)
//
#include <hip/hip_runtime.h>

#define B_DIM 64
#define T_DIM 1024
#define L_DIM 16
#define K_DIM 64
#define LOG2E 1.44269504088896340736f
#define LN2   0.69314718055994530942f

typedef float f32x2 __attribute__((ext_vector_type(2)));
typedef float f32x4 __attribute__((ext_vector_type(4)));

__device__ __forceinline__ float ex2(float x) { return __builtin_amdgcn_exp2f(x); }
__device__ __forceinline__ float lg2(float x) { return __builtin_amdgcn_logf(x); }

#define SB0() __builtin_amdgcn_sched_barrier(0)
#define BAR() __builtin_amdgcn_s_barrier()

__device__ __forceinline__ void stage16(const float* g, float* l) {
  __builtin_amdgcn_global_load_lds(
      (const __attribute__((address_space(1))) unsigned int*)g,
      (__attribute__((address_space(3))) unsigned int*)l, 16, 0, 0);
}
__device__ __forceinline__ unsigned int lds_addr(const float* p) {
  return (unsigned int)(size_t)(__attribute__((address_space(3))) const float*)p;
}
template<int IMM> __device__ __forceinline__ float dsr32(unsigned int a) {
  float d; asm volatile("ds_read_b32 %0, %1 offset:%2" : "=v"(d) : "v"(a), "n"(IMM)); return d;
}
template<int IMM> __device__ __forceinline__ f32x2 dsr64(unsigned int a) {
  f32x2 d; asm volatile("ds_read_b64 %0, %1 offset:%2" : "=v"(d) : "v"(a), "n"(IMM)); return d;
}
template<int IMM> __device__ __forceinline__ f32x4 dsr128(unsigned int a) {
  f32x4 d; asm volatile("ds_read_b128 %0, %1 offset:%2" : "=v"(d) : "v"(a), "n"(IMM)); return d;
}
template<int IMM> __device__ __forceinline__ void dsw32(unsigned int a, float v) {
  asm volatile("ds_write_b32 %0, %1 offset:%2" :: "v"(a), "v"(v), "n"(IMM));
}
template<int IMM> __device__ __forceinline__ void dsw64(unsigned int a, f32x2 v) {
  asm volatile("ds_write_b64 %0, %1 offset:%2" :: "v"(a), "v"(v), "n"(IMM));
}
template<int N> __device__ __forceinline__ void waitv() {
  if constexpr (N == 20)      asm volatile("s_waitcnt vmcnt(20)");
  else if constexpr (N == 16) asm volatile("s_waitcnt vmcnt(16)");
  else if constexpr (N == 12) asm volatile("s_waitcnt vmcnt(12)");
  else if constexpr (N == 8)  asm volatile("s_waitcnt vmcnt(8)");
  else if constexpr (N == 4)  asm volatile("s_waitcnt vmcnt(4)");
  else                        asm volatile("s_waitcnt vmcnt(0)");
}
template<int N> __device__ __forceinline__ void waitl() {
  if constexpr (N == 15)      asm volatile("s_waitcnt lgkmcnt(15)");
  else if constexpr (N == 14) asm volatile("s_waitcnt lgkmcnt(14)");
  else if constexpr (N == 10) asm volatile("s_waitcnt lgkmcnt(10)");
  else if constexpr (N == 6)  asm volatile("s_waitcnt lgkmcnt(6)");
  else if constexpr (N == 2)  asm volatile("s_waitcnt lgkmcnt(2)");
  else                        asm volatile("s_waitcnt lgkmcnt(0)" ::: "memory");
}

// ---------------- LDS layout (BYTE offsets) --------------------------------
// ea[2][64]   @0      (slot t&1 holds EA_t)
// gg[2][64]   @512    (slot t&1 holds g_t)
// pp[2][64]   @1024   (slot t&1 holds partial_t)
// ef01[4][64x2] @1536 (slot t&3 holds {ef_t[0],ef_t[1]} per lane)
// feat ring[8][1024]  @20992 (slot t&7 holds row t)
#define LDSF 13440

// window t: P=(t-1)&15. w0: recursion step t. w1: stage row t+8, read raw
// feat row t+2 -> regs, exps ef_{t+1}, ring update (g_{t-1}), partial_{t+1}.
template<int P, bool STG, int WVM, bool RDN, bool EFON>
__device__ __forceinline__ void window_impl(
    int wid, float* sh, const float*& pg,
    float& EA, float& gprev, float& u, float& logR,
    float (&ring)[16], const float (&fnp)[16], float (&fnn)[16],
    const f32x2 (&Ec)[32],
    unsigned int aU, unsigned int aL, unsigned int aE2)
{
  constexpr bool REN   = ((P + 1) & 3) == 0;  // t % 4 == 0
  constexpr bool SAVEU = ((P + 1) & 3) == 3;  // t % 4 == 3
  if (wid == 0) {
    constexpr int EAr = (P & 1) * 256;
    constexpr int EAw = ((P + 1) & 1) * 256;
    constexpr int GGw = 512 + ((P + 1) & 1) * 256;
    constexpr int PPr = 1024 + ((P + 1) & 1) * 256;
    constexpr int E01 = 1536 + ((P + 1) & 3) * 512;
    f32x4 q0  = dsr128<EAr + 0>(aU),   q1  = dsr128<EAr + 16>(aU);
    f32x4 q2  = dsr128<EAr + 32>(aU),  q3  = dsr128<EAr + 48>(aU);
    f32x4 q4  = dsr128<EAr + 64>(aU),  q5  = dsr128<EAr + 80>(aU);
    f32x4 q6  = dsr128<EAr + 96>(aU),  q7  = dsr128<EAr + 112>(aU);
    f32x4 q8  = dsr128<EAr + 128>(aU), q9  = dsr128<EAr + 144>(aU);
    f32x4 q10 = dsr128<EAr + 160>(aU), q11 = dsr128<EAr + 176>(aU);
    f32x4 q12 = dsr128<EAr + 192>(aU), q13 = dsr128<EAr + 208>(aU);
    f32x4 q14 = dsr128<EAr + 224>(aU), q15 = dsr128<EAr + 240>(aU);
    f32x2 ef01 = dsr64<E01>(aE2);      // queue pos 17
    float ppv  = dsr32<PPr>(aL);       // queue pos 18
    f32x2 A0 = {0.f, 0.f}, A1 = {0.f, 0.f}, A2 = {0.f, 0.f}, A3 = {0.f, 0.f};
#define MV(j, q, Aa, Ab)                                           \
  { f32x2 _x = {q.x, q.y}, _y = {q.z, q.w};                        \
    Aa = __builtin_elementwise_fma(_x, Ec[2 * (j)], Aa);           \
    Ab = __builtin_elementwise_fma(_y, Ec[2 * (j) + 1], Ab); }
    waitl<14>(); SB0();   // quads 0-3
    MV(0, q0, A0, A1)  MV(1, q1, A2, A3)  MV(2, q2, A0, A1)  MV(3, q3, A2, A3)
    waitl<10>(); SB0();   // quads 4-7
    MV(4, q4, A0, A1)  MV(5, q5, A2, A3)  MV(6, q6, A0, A1)  MV(7, q7, A2, A3)
    waitl<6>(); SB0();    // quads 8-11
    MV(8, q8, A0, A1)  MV(9, q9, A2, A3)  MV(10, q10, A0, A1) MV(11, q11, A2, A3)
    waitl<2>(); SB0();    // quads 12-15
    MV(12, q12, A0, A1) MV(13, q13, A2, A3) MV(14, q14, A0, A1) MV(15, q15, A2, A3)
#undef MV
    waitl<0>(); SB0();    // ef01, pp
    f32x2 G = (A0 + A1) + (A2 + A3);
    float g = G.x + G.y;
    float br = fmaf(ef01.x, g, fmaf(ef01.y, gprev, ppv));
    float gst = g;
    if (REN) {
      unsigned int ub = __float_as_uint(u);
      int e = (int)((ub >> 23) & 255u);
      float s = __uint_as_float((unsigned int)(254 - e) << 23);
      logR += (float)(e - 127);
      br *= s; gst = g * s;
    }
    EA = br;
    dsw32<EAw>(aL, EA);
    dsw32<GGw>(aL, gst);
    gprev = gst;
    if (SAVEU) u = __uint_as_float(__builtin_amdgcn_readfirstlane(__float_as_uint(EA)));
    waitl<0>();
  } else {
    if constexpr (WVM >= 0) { waitv<WVM>(); SB0(); }
    if (STG) {
      float* dst = sh + 5248 + ((P + 1) & 7) * 1024;  // slot (t+8)&7 == t&7
      stage16(pg + 0,   dst + 0);
      stage16(pg + 256, dst + 256);
      stage16(pg + 512, dst + 512);
      stage16(pg + 768, dst + 768);
      pg += T_DIM;
    }
    float gv = 0.f, uv = 0.f;
    if (EFON) {
      constexpr int GGr = 512 + (P & 1) * 256;
      gv = dsr32<GGr>(aL);
      if (REN) { constexpr int UR = (P & 1) * 256; uv = dsr32<UR>(aU); }
    }
    if constexpr (RDN) {
      constexpr int FR = 20992 + ((P + 3) & 7) * 4096;  // row t+2
      fnn[0]  = dsr32<FR + 0>(aL);    fnn[1]  = dsr32<FR + 256>(aL);
      fnn[2]  = dsr32<FR + 512>(aL);  fnn[3]  = dsr32<FR + 768>(aL);
      fnn[4]  = dsr32<FR + 1024>(aL); fnn[5]  = dsr32<FR + 1280>(aL);
      fnn[6]  = dsr32<FR + 1536>(aL); fnn[7]  = dsr32<FR + 1792>(aL);
      fnn[8]  = dsr32<FR + 2048>(aL); fnn[9]  = dsr32<FR + 2304>(aL);
      fnn[10] = dsr32<FR + 2560>(aL); fnn[11] = dsr32<FR + 2816>(aL);
      fnn[12] = dsr32<FR + 3072>(aL); fnn[13] = dsr32<FR + 3328>(aL);
      fnn[14] = dsr32<FR + 3584>(aL); fnn[15] = dsr32<FR + 3840>(aL);
    }
    if (EFON) {
      // exps of fnp (row t+1, read last window; regs — no wait needed)
      float e0  = ex2(fnp[0]  * LOG2E), e1  = ex2(fnp[1]  * LOG2E);
      float e2_ = ex2(fnp[2]  * LOG2E), e3_ = ex2(fnp[3]  * LOG2E);
      float e4_ = ex2(fnp[4]  * LOG2E), e5_ = ex2(fnp[5]  * LOG2E);
      float e6_ = ex2(fnp[6]  * LOG2E), e7_ = ex2(fnp[7]  * LOG2E);
      float e8_ = ex2(fnp[8]  * LOG2E), e9_ = ex2(fnp[9]  * LOG2E);
      float e10_ = ex2(fnp[10] * LOG2E), e11_ = ex2(fnp[11] * LOG2E);
      float e12_ = ex2(fnp[12] * LOG2E), e13_ = ex2(fnp[13] * LOG2E);
      float e14_ = ex2(fnp[14] * LOG2E), e15_ = ex2(fnp[15] * LOG2E);
      if constexpr (RDN) { waitl<15>(); } else { waitl<0>(); }  // gg (+u) retired
      SB0();
      ring[P & 15] = gv;                  // g_{t-1}
      if (REN) {
        unsigned int ub = __float_as_uint(uv);
        int e = (int)((ub >> 23) & 255u);
        float s = __uint_as_float((unsigned int)(254 - e) << 23);
#pragma unroll
        for (int i = 0; i < 16; ++i) ring[i] *= s;
      }
      // partial_{t+1} = sum_{l=2..15} ef_{t+1}[l] * g_{t+1-l}
      float p0 = e2_ * ring[P & 15];
      float p1 = e3_ * ring[(P + 15) & 15];
      float p2 = e4_ * ring[(P + 14) & 15];
      float p3 = e5_ * ring[(P + 13) & 15];
      p0 = fmaf(e6_,  ring[(P + 12) & 15], p0);
      p1 = fmaf(e7_,  ring[(P + 11) & 15], p1);
      p2 = fmaf(e8_,  ring[(P + 10) & 15], p2);
      p3 = fmaf(e9_,  ring[(P + 9)  & 15], p3);
      p0 = fmaf(e10_, ring[(P + 8)  & 15], p0);
      p1 = fmaf(e11_, ring[(P + 7)  & 15], p1);
      p2 = fmaf(e12_, ring[(P + 6)  & 15], p2);
      p3 = fmaf(e13_, ring[(P + 5)  & 15], p3);
      p0 = fmaf(e14_, ring[(P + 4)  & 15], p0);
      p1 = fmaf(e15_, ring[(P + 3)  & 15], p1);
      float pv = (p0 + p1) + (p2 + p3);
      constexpr int E01w = 1536 + ((P + 2) & 3) * 512;  // slot (t+1)&3
      constexpr int PPw  = 1024 + (P & 1) * 256;        // slot (t+1)&1
      f32x2 ef01w = {e0, e1};
      dsw64<E01w>(aE2, ef01w);
      dsw32<PPw>(aL, pv);
    }
    waitl<0>();
  }
  SB0();
  BAR();
}

// parity dispatch: fn double-buffer statically named (rule #20)
template<int P, bool STG, int WVM, bool RDN, bool EFON>
__device__ __forceinline__ void window(
    int wid, float* sh, const float*& pg,
    float& EA, float& gprev, float& u, float& logR,
    float (&ring)[16], float (&fnA)[16], float (&fnB)[16],
    const f32x2 (&Ec)[32],
    unsigned int aU, unsigned int aL, unsigned int aE2)
{
  if constexpr ((P & 1) == 0)   // t odd: prev=fnB, next=fnA
    window_impl<P, STG, WVM, RDN, EFON>(wid, sh, pg, EA, gprev, u, logR, ring, fnB, fnA, Ec, aU, aL, aE2);
  else                          // t even: prev=fnA, next=fnB
    window_impl<P, STG, WVM, RDN, EFON>(wid, sh, pg, EA, gprev, u, logR, ring, fnA, fnB, Ec, aU, aL, aE2);
}

#define CHW(p) window<(p), true, 16, true, true>(wid, sh, pg, EA, gprev, u, logR, ring, fnA, fnB, Ec, aU, aL, aE2)
#define CHT(p, s_, w_, r_, e_) window<(p), (s_), (w_), (r_), (e_)>(wid, sh, pg, EA, gprev, u, logR, ring, fnA, fnB, Ec, aU, aL, aE2)

__global__ __launch_bounds__(128, 1) void fused_kernel(
    const float* __restrict__ feat, const float* __restrict__ trans,
    const int* __restrict__ tag, float* __restrict__ out)
{
  const int b = blockIdx.x;
  const int tid = threadIdx.x;
  const int lane = tid & 63;
  const int wid = tid >> 6;
  const float* fb = feat + (size_t)b * T_DIM * L_DIM * K_DIM;

  __shared__ __align__(16) float sh[LDSF];

  unsigned int aU  = lds_addr(sh);              // uniform base (broadcast reads)
  unsigned int aL  = lds_addr(sh) + lane * 4;   // lane-strided b32 base
  unsigned int aE2 = lds_addr(sh) + lane * 8;   // lane-strided b64 base
  asm volatile("" : "+v"(aU), "+v"(aL), "+v"(aE2));

  f32x2 Ec[32];
  float ring[16], fnA[16], fnB[16];
#pragma unroll
  for (int i = 0; i < 16; ++i) { ring[i] = 0.f; fnA[i] = 0.f; fnB[i] = 0.f; }
  float EA = 0.f, gprev = 0.f, u = 1.0f, logR = 0.0f;
  const float* pg = fb + T_DIM + 4 * lane;

  // ---------------- prologue ----------------
  if (wid == 1) {
    // stage rows 1..8 into ring slots (32 loads in flight)
#pragma unroll
    for (int r = 1; r <= 8; ++r) {
      float* dst = sh + 5248 + (r & 7) * 1024;
      stage16(pg + 0,   dst + 0);
      stage16(pg + 256, dst + 256);
      stage16(pg + 512, dst + 512);
      stage16(pg + 768, dst + 768);
      pg += T_DIM;
    }
    waitv<20>(); SB0();   // rows 1..3 landed
    // ef_1 needs only l=0,1 (partial_1 = 0, g_0 = 0)
    float w0_ = dsr32<20992 + 4096 + 0>(aL);
    float w1_ = dsr32<20992 + 4096 + 256>(aL);
    // raw row 2 -> fnB (consumed at window t=1, P=0 even -> prev=fnB)
    fnB[0]  = dsr32<20992 + 8192 + 0>(aL);    fnB[1]  = dsr32<20992 + 8192 + 256>(aL);
    fnB[2]  = dsr32<20992 + 8192 + 512>(aL);  fnB[3]  = dsr32<20992 + 8192 + 768>(aL);
    fnB[4]  = dsr32<20992 + 8192 + 1024>(aL); fnB[5]  = dsr32<20992 + 8192 + 1280>(aL);
    fnB[6]  = dsr32<20992 + 8192 + 1536>(aL); fnB[7]  = dsr32<20992 + 8192 + 1792>(aL);
    fnB[8]  = dsr32<20992 + 8192 + 2048>(aL); fnB[9]  = dsr32<20992 + 8192 + 2304>(aL);
    fnB[10] = dsr32<20992 + 8192 + 2560>(aL); fnB[11] = dsr32<20992 + 8192 + 2816>(aL);
    fnB[12] = dsr32<20992 + 8192 + 3072>(aL); fnB[13] = dsr32<20992 + 8192 + 3328>(aL);
    fnB[14] = dsr32<20992 + 8192 + 3584>(aL); fnB[15] = dsr32<20992 + 8192 + 3840>(aL);
    waitl<0>(); SB0();
    f32x2 e01 = {ex2(w0_ * LOG2E), ex2(w1_ * LOG2E)};
    dsw64<1536 + 512>(aE2, e01);   // ef01 slot 1 (step t=1)
    dsw32<1280>(aL, 0.f);          // pp slot 1 (partial_1 = 0)
    waitl<0>();
  } else {
    // E columns, packed pairs, pinned in VGPRs
#pragma unroll
    for (int k = 0; k < 32; ++k) {
      f32x2 t2 = {ex2(trans[(2 * k) * K_DIM + lane] * LOG2E),
                  ex2(trans[(2 * k + 1) * K_DIM + lane] * LOG2E)};
      Ec[k] = t2;
    }
#pragma unroll
    for (int k = 0; k < 32; ++k) asm volatile("" : "+v"(Ec[k]));
    EA = ex2(fb[lane] * LOG2E);    // EA_0
    dsw32<0>(aL, EA);              // ea slot 0
    dsw32<512>(aL, 0.f);           // gg slot 0 (g_0 = 0)
    waitl<0>();
  }
  SB0(); BAR();

  // ---------------- main: t = 1..1008 (63 chunks of 16) ----------------
#pragma unroll 1
  for (int c = 0; c < 63; ++c) {
    CHW(0);  CHW(1);  CHW(2);  CHW(3);
    CHW(4);  CHW(5);  CHW(6);  CHW(7);
    CHW(8);  CHW(9);  CHW(10); CHW(11);
    CHW(12); CHW(13); CHW(14); CHW(15);
  }
  // tail: t = 1009..1023 (P = 0..14)
  CHT(0,  true,  16, true,  true);  CHT(1,  true,  16, true,  true);
  CHT(2,  true,  16, true,  true);  CHT(3,  true,  16, true,  true);
  CHT(4,  true,  16, true,  true);  CHT(5,  true,  16, true,  true);
  CHT(6,  true,  16, true,  true);                     // t=1015 stages row 1023
  CHT(7,  false, 12, true,  true);  CHT(8,  false, 8,  true,  true);
  CHT(9,  false, 4,  true,  true);  CHT(10, false, 0,  true,  true);
  CHT(11, false, -1, true,  true);  CHT(12, false, -1, true,  true);  // t=1021 reads row 1023
  CHT(13, false, -1, false, true);                     // t=1022: last ef/pp (for t=1023)
  CHT(14, false, -1, false, false);                    // t=1023: recursion only

  // ---------------- epilogue: partition + score ----------------
  if (wid == 0) {
    float ssum = EA;
    for (int off = 32; off >= 1; off >>= 1) ssum += __shfl_xor(ssum, off, 64);
    float Pv = (logR + lg2(ssum)) * LN2;
    if (lane == 0) sh[0] = Pv;
  }
  __syncthreads();

  const int* tg = tag + b * T_DIM;
  float sc = 0.f;
#pragma unroll
  for (int k = 0; k < 8; ++k) {
    int t = tid + k * 128;
    if (t >= 1) {
      int tc  = tg[t];
      int tm1 = tg[t - 1];
      int ls = 0;
      if (t >= 2) {
        int tm2 = tg[t - 2];
        ls = (tm2 == tm1) ? (tm1 < (L_DIM - 1) ? tm1 : (L_DIM - 1)) : 0;
      }
      sc += fb[((size_t)t * L_DIM + ls) * K_DIM + tc] + trans[tm1 * K_DIM + tc];
    }
  }
  if (tid == 0) sc += fb[tg[0]];
  for (int off = 32; off >= 1; off >>= 1) sc += __shfl_xor(sc, off, 64);
  if (lane == 0) sh[1 + wid] = sc;
  __syncthreads();
  if (tid == 0) out[b] = (sh[1] + sh[2]) - sh[0];
}

extern "C" void kernel_launch(void* const* d_in, const int* in_sizes, int n_in,
                              void* d_out, int out_size, void* d_ws, size_t ws_size,
                              hipStream_t stream) {
  const float* feat  = (const float*)d_in[0];
  const float* trans = (const float*)d_in[1];
  const int*   tag   = (const int*)d_in[2];
  float* out = (float*)d_out;

  fused_kernel<<<B_DIM, 128, 0, stream>>>(feat, trans, tag, out);
}

// Round 12
// 303.148 us; speedup vs baseline: 1.0175x; 1.0175x over previous
//
#include <hip/hip_runtime.h>

#define B_DIM 64
#define T_DIM 1024
#define L_DIM 16
#define K_DIM 64
#define LOG2E 1.44269504088896340736f
#define LN2   0.69314718055994530942f

typedef float f32x2 __attribute__((ext_vector_type(2)));
typedef float f32x4 __attribute__((ext_vector_type(4)));
typedef __fp16 h16x2 __attribute__((ext_vector_type(2)));

__device__ __forceinline__ float ex2(float x) { return __builtin_amdgcn_exp2f(x); }
__device__ __forceinline__ float lg2(float x) { return __builtin_amdgcn_logf(x); }

#define SB0() __builtin_amdgcn_sched_barrier(0)
#define BAR() __builtin_amdgcn_s_barrier()

__device__ __forceinline__ unsigned int lds_addr(const float* p) {
  return (unsigned int)(size_t)(__attribute__((address_space(3))) const float*)p;
}
template<int IMM> __device__ __forceinline__ float dsr32(unsigned int a) {
  float d; asm volatile("ds_read_b32 %0, %1 offset:%2" : "=v"(d) : "v"(a), "n"(IMM)); return d;
}
template<int IMM> __device__ __forceinline__ unsigned int dsru16(unsigned int a) {
  unsigned int d; asm volatile("ds_read_u16 %0, %1 offset:%2" : "=v"(d) : "v"(a), "n"(IMM)); return d;
}
template<int IMM> __device__ __forceinline__ f32x2 dsr64(unsigned int a) {
  f32x2 d; asm volatile("ds_read_b64 %0, %1 offset:%2" : "=v"(d) : "v"(a), "n"(IMM)); return d;
}
template<int IMM> __device__ __forceinline__ f32x4 dsr128(unsigned int a) {
  f32x4 d; asm volatile("ds_read_b128 %0, %1 offset:%2" : "=v"(d) : "v"(a), "n"(IMM)); return d;
}
template<int IMM> __device__ __forceinline__ void dsw32(unsigned int a, float v) {
  asm volatile("ds_write_b32 %0, %1 offset:%2" :: "v"(a), "v"(v), "n"(IMM));
}
template<int IMM> __device__ __forceinline__ void dsw64(unsigned int a, f32x2 v) {
  asm volatile("ds_write_b64 %0, %1 offset:%2" :: "v"(a), "v"(v), "n"(IMM));
}
template<int IMM> __device__ __forceinline__ void dsw16(unsigned int a, unsigned int v) {
  asm volatile("ds_write_b16 %0, %1 offset:%2" :: "v"(a), "v"(v), "n"(IMM));
}
template<int IMM> __device__ __forceinline__ void gld(float& d, const float* p) {
  asm volatile("global_load_dword %0, %1, off offset:%2" : "=v"(d) : "v"(p), "n"(IMM));
}
template<int N> __device__ __forceinline__ void waitv() {
  if constexpr (N == 48)      asm volatile("s_waitcnt vmcnt(48)");
  else if constexpr (N == 32) asm volatile("s_waitcnt vmcnt(32)");
  else if constexpr (N == 16) asm volatile("s_waitcnt vmcnt(16)");
  else                        asm volatile("s_waitcnt vmcnt(0)");
}
template<int N> __device__ __forceinline__ void waitl() {
  if constexpr (N == 6)       asm volatile("s_waitcnt lgkmcnt(6)");
  else if constexpr (N == 2)  asm volatile("s_waitcnt lgkmcnt(2)");
  else                        asm volatile("s_waitcnt lgkmcnt(0)" ::: "memory");
}
__device__ __forceinline__ float fdot2(h16x2 a, h16x2 b, float c) {
#if __has_builtin(__builtin_amdgcn_fdot2)
  return __builtin_amdgcn_fdot2(a, b, c, false);
#else
  float d; asm("v_dot2_f32_f16 %0, %1, %2, %3" : "=v"(d) : "v"(a), "v"(b), "v"(c));
  return d;
#endif
}

// ---------------- LDS layout (BYTE offsets), total 3328 B -------------------
// ea16[2][64]  @0     (f16, slot t&1 holds scaled ea_t)
// gg[2][64]    @256   (f32, slot t&1 holds scaled g_t)
// pp[2][64]    @768   (f32, slot (t)&1 holds partial_t ... w0 reads slot t&1)
// ef01[4][64x2]@1280  (f32 pairs, slot t&3 holds {ef_t[0], ef_t[1]})

#define LDROW(buf) do { \
  gld<0>(buf[0], pgl);     gld<256>(buf[1], pgl);   gld<512>(buf[2], pgl);   gld<768>(buf[3], pgl);   \
  gld<1024>(buf[4], pgl);  gld<1280>(buf[5], pgl);  gld<1536>(buf[6], pgl);  gld<1792>(buf[7], pgl);  \
  gld<2048>(buf[8], pgl);  gld<2304>(buf[9], pgl);  gld<2560>(buf[10], pgl); gld<2816>(buf[11], pgl); \
  gld<3072>(buf[12], pgl); gld<3328>(buf[13], pgl); gld<3584>(buf[14], pgl); gld<3840>(buf[15], pgl); \
  pgl += T_DIM; } while (0)

// window t: P=(t-1)&15. w0: recursion step t (f16 ea broadcast, dot2 matvec).
// w1: issue row t+4 -> regs, exps ef_{t+1} from row t+1 regs, ring/partial.
template<int P, bool STG, int WVM, bool EFON>
__device__ __forceinline__ void window_impl(
    int wid, const float*& pgl,
    float& EA, float& gprev, float& logR,
    float (&ring)[16], const float (&fnU)[16], float (&fnL)[16],
    const unsigned int (&Ec)[32],
    unsigned int aU, unsigned int aL, unsigned int aH, unsigned int aE2)
{
  if (wid == 0) {
    constexpr int EAr = (P & 1) * 128;          // ea_{t-1}
    constexpr int EAw = ((P + 1) & 1) * 128;    // ea_t
    constexpr int GGw = 256 + ((P + 1) & 1) * 256;
    constexpr int PPr = 768 + ((P + 1) & 1) * 256;
    constexpr int E01 = 1280 + ((P + 1) & 3) * 512;
    f32x4 q0 = dsr128<EAr + 0>(aU),  q1 = dsr128<EAr + 16>(aU);
    f32x4 q2 = dsr128<EAr + 32>(aU), q3 = dsr128<EAr + 48>(aU);
    f32x4 q4 = dsr128<EAr + 64>(aU), q5 = dsr128<EAr + 80>(aU);
    f32x4 q6 = dsr128<EAr + 96>(aU), q7 = dsr128<EAr + 112>(aU);
    f32x2 ef01 = dsr64<E01>(aE2);
    float ppv  = dsr32<PPr>(aL);
    float A0 = 0.f, A1 = 0.f, A2 = 0.f, A3 = 0.f;
#define DOTQ(j, q)                                                               \
    A0 = fdot2(__builtin_bit_cast(h16x2, q.x), __builtin_bit_cast(h16x2, Ec[4*(j)+0]), A0); \
    A1 = fdot2(__builtin_bit_cast(h16x2, q.y), __builtin_bit_cast(h16x2, Ec[4*(j)+1]), A1); \
    A2 = fdot2(__builtin_bit_cast(h16x2, q.z), __builtin_bit_cast(h16x2, Ec[4*(j)+2]), A2); \
    A3 = fdot2(__builtin_bit_cast(h16x2, q.w), __builtin_bit_cast(h16x2, Ec[4*(j)+3]), A3);
    waitl<6>(); SB0();
    // renorm scale from stored f16 bits of ea_{t-1}[0] (uniform in q0.x)
    unsigned int bits = __float_as_uint(q0.x);
    unsigned int ue = (bits >> 10) & 31u;
    float r  = __uint_as_float((138u - ue) << 23);   // 2^(11-ue); BIAS=-4
    float dl = (float)(int)ue - 11.0f;               // logR increment
    DOTQ(0, q0) DOTQ(1, q1) DOTQ(2, q2) DOTQ(3, q3)
    waitl<2>(); SB0();
    DOTQ(4, q4) DOTQ(5, q5) DOTQ(6, q6) DOTQ(7, q7)
#undef DOTQ
    waitl<0>(); SB0();
    float g  = (A0 + A1) + (A2 + A3);
    float EAn = fmaf(ef01.x, g, fmaf(ef01.y, gprev, ppv));
    float EAs = EAn * r, gs = g * r;
    logR += dl;
    dsw16<EAw>(aH, __builtin_bit_cast(unsigned int,
                   __builtin_amdgcn_cvt_pkrtz(EAs, 0.0f)));
    dsw32<GGw>(aL, gs);
    gprev = gs; EA = EAs;
    waitl<0>();
  } else {
    if (STG) { LDROW(fnL); }
    if (EFON) {
      constexpr int GGr = 256 + (P & 1) * 256;   // g_{t-1}
      constexpr int EAu = (P & 1) * 128;         // ea_{t-1}[0] f16 bits
      float gv = dsr32<GGr>(aL);
      unsigned int ub = dsru16<EAu>(aU);
      if constexpr (WVM >= 0) { waitv<WVM>(); SB0(); }  // row t+1 regs ready
      waitl<0>(); SB0();
      unsigned int ue = (ub >> 10) & 31u;
      float r = __uint_as_float((138u - ue) << 23);
      float ex0 = ex2(fnU[0] * LOG2E),  ex1 = ex2(fnU[1] * LOG2E);
      float ex2_ = ex2(fnU[2] * LOG2E), ex3 = ex2(fnU[3] * LOG2E);
      float ex4 = ex2(fnU[4] * LOG2E),  ex5 = ex2(fnU[5] * LOG2E);
      float ex6 = ex2(fnU[6] * LOG2E),  ex7 = ex2(fnU[7] * LOG2E);
      float ex8 = ex2(fnU[8] * LOG2E),  ex9 = ex2(fnU[9] * LOG2E);
      float ex10 = ex2(fnU[10] * LOG2E), ex11 = ex2(fnU[11] * LOG2E);
      float ex12 = ex2(fnU[12] * LOG2E), ex13 = ex2(fnU[13] * LOG2E);
      float ex14 = ex2(fnU[14] * LOG2E), ex15 = ex2(fnU[15] * LOG2E);
      ring[P & 15] = gv;                 // domain t-1 matches ring
#pragma unroll
      for (int i = 0; i < 16; ++i) ring[i] *= r;   // -> domain t
      float p0 = ex2_ * ring[P & 15];
      float p1 = ex3 * ring[(P + 15) & 15];
      float p2 = ex4 * ring[(P + 14) & 15];
      float p3 = ex5 * ring[(P + 13) & 15];
      p0 = fmaf(ex6,  ring[(P + 12) & 15], p0);
      p1 = fmaf(ex7,  ring[(P + 11) & 15], p1);
      p2 = fmaf(ex8,  ring[(P + 10) & 15], p2);
      p3 = fmaf(ex9,  ring[(P + 9)  & 15], p3);
      p0 = fmaf(ex10, ring[(P + 8)  & 15], p0);
      p1 = fmaf(ex11, ring[(P + 7)  & 15], p1);
      p2 = fmaf(ex12, ring[(P + 6)  & 15], p2);
      p3 = fmaf(ex13, ring[(P + 5)  & 15], p3);
      p0 = fmaf(ex14, ring[(P + 4)  & 15], p0);
      p1 = fmaf(ex15, ring[(P + 3)  & 15], p1);
      float pv = (p0 + p1) + (p2 + p3);
      constexpr int E01w = 1280 + ((P + 2) & 3) * 512;
      constexpr int PPw  = 768 + (P & 1) * 256;
      f32x2 w01 = {ex0, ex1};
      dsw64<E01w>(aE2, w01);
      dsw32<PPw>(aL, pv);
      waitl<0>();
    } else {
      if constexpr (WVM >= 0) { waitv<WVM>(); }
    }
  }
  SB0();
  BAR();
}

// static fn-buffer rotation: use row t+1 = fn[(P+2)&3], load row t+4 = fn[(P+1)&3]
template<int P, bool STG, int WVM, bool EFON>
__device__ __forceinline__ void window(
    int wid, const float*& pgl, float& EA, float& gprev, float& logR,
    float (&ring)[16], float (&fn0)[16], float (&fn1)[16],
    float (&fn2)[16], float (&fn3)[16],
    const unsigned int (&Ec)[32],
    unsigned int aU, unsigned int aL, unsigned int aH, unsigned int aE2)
{
  if constexpr ((P & 3) == 0)
    window_impl<P, STG, WVM, EFON>(wid, pgl, EA, gprev, logR, ring, fn2, fn1, Ec, aU, aL, aH, aE2);
  else if constexpr ((P & 3) == 1)
    window_impl<P, STG, WVM, EFON>(wid, pgl, EA, gprev, logR, ring, fn3, fn2, Ec, aU, aL, aH, aE2);
  else if constexpr ((P & 3) == 2)
    window_impl<P, STG, WVM, EFON>(wid, pgl, EA, gprev, logR, ring, fn0, fn3, Ec, aU, aL, aH, aE2);
  else
    window_impl<P, STG, WVM, EFON>(wid, pgl, EA, gprev, logR, ring, fn1, fn0, Ec, aU, aL, aH, aE2);
}

#define CHW(p) window<(p), true, 48, true>(wid, pgl, EA, gprev, logR, ring, fn0, fn1, fn2, fn3, Ec, aU, aL, aH, aE2)
#define CHT(p, s_, w_, e_) window<(p), (s_), (w_), (e_)>(wid, pgl, EA, gprev, logR, ring, fn0, fn1, fn2, fn3, Ec, aU, aL, aH, aE2)

__global__ __launch_bounds__(128, 1) void fused_kernel(
    const float* __restrict__ feat, const float* __restrict__ trans,
    const int* __restrict__ tag, float* __restrict__ out)
{
  const int b = blockIdx.x;
  const int tid = threadIdx.x;
  const int lane = tid & 63;
  const int wid = tid >> 6;
  const float* fb = feat + (size_t)b * T_DIM * L_DIM * K_DIM;

  __shared__ __align__(16) float sh[832];   // 3328 B

  unsigned int aU  = lds_addr(sh);              // uniform (broadcast quads, u16)
  unsigned int aL  = lds_addr(sh) + lane * 4;   // b32 lane-strided
  unsigned int aH  = lds_addr(sh) + lane * 2;   // b16 lane-strided (ea write)
  unsigned int aE2 = lds_addr(sh) + lane * 8;   // b64 lane-strided (ef01)
  asm volatile("" : "+v"(aU), "+v"(aL), "+v"(aH), "+v"(aE2));

  unsigned int Ec[32];
  float ring[16], fn0[16], fn1[16], fn2[16], fn3[16];
#pragma unroll
  for (int i = 0; i < 16; ++i) ring[i] = 0.f;
  float EA = 0.f, gprev = 0.f, logR = 0.0f;
  const float* pgl = fb + T_DIM + lane;   // row 1 base for this lane

  // ---------------- prologue ----------------
  if (wid == 1) {
    LDROW(fn1);  // row 1
    LDROW(fn2);  // row 2
    LDROW(fn3);  // row 3
    LDROW(fn0);  // row 4
    waitv<48>(); SB0();                  // row 1 regs ready
    float ex0 = ex2(fn1[0] * LOG2E), ex1 = ex2(fn1[1] * LOG2E);
    f32x2 w01 = {ex0, ex1};
    dsw64<1280 + 512>(aE2, w01);         // ef01 slot 1 (t=1)
    dsw32<768 + 256>(aL, 0.f);           // pp slot 1 = 0
    waitl<0>();
  } else {
    // Ec: packed f16 pairs of E[kp][lane] = 2^(trans*log2e)
#pragma unroll
    for (int k = 0; k < 32; ++k) {
      float e0 = ex2(trans[(2 * k) * K_DIM + lane] * LOG2E);
      float e1 = ex2(trans[(2 * k + 1) * K_DIM + lane] * LOG2E);
      Ec[k] = __builtin_bit_cast(unsigned int, __builtin_amdgcn_cvt_pkrtz(e0, e1));
    }
#pragma unroll
    for (int k = 0; k < 32; ++k) asm volatile("" : "+v"(Ec[k]));
    float EA0 = ex2(fb[lane] * LOG2E);   // EA_0 (unscaled, logR = 0)
    dsw16<0>(aH, __builtin_bit_cast(unsigned int,
                 __builtin_amdgcn_cvt_pkrtz(EA0, 0.0f)));  // ea slot 0
    dsw32<256>(aL, 0.f);                 // gg slot 0 (g_0 = 0)
    waitl<0>();
  }
  SB0(); BAR();

  // ---------------- main: t = 1..1008 (63 chunks of 16) ----------------
#pragma unroll 1
  for (int c = 0; c < 63; ++c) {
    CHW(0);  CHW(1);  CHW(2);  CHW(3);
    CHW(4);  CHW(5);  CHW(6);  CHW(7);
    CHW(8);  CHW(9);  CHW(10); CHW(11);
    CHW(12); CHW(13); CHW(14); CHW(15);
  }
  // tail: t = 1009..1023 (P = 0..14); last issue at t=1019 (row 1023)
  CHT(0,  true,  48, true); CHT(1,  true,  48, true);
  CHT(2,  true,  48, true); CHT(3,  true,  48, true);
  CHT(4,  true,  48, true); CHT(5,  true,  48, true);
  CHT(6,  true,  48, true); CHT(7,  true,  48, true);
  CHT(8,  true,  48, true); CHT(9,  true,  48, true);
  CHT(10, true,  48, true);                       // t=1019
  CHT(11, false, 32, true); CHT(12, false, 16, true);
  CHT(13, false, 0,  true);                       // t=1022: ef_1023
  CHT(14, false, -1, false);                      // t=1023: recursion only

  // ---------------- epilogue: partition + score ----------------
  if (wid == 0) {
    float ssum = EA;
    for (int off = 32; off >= 1; off >>= 1) ssum += __shfl_xor(ssum, off, 64);
    float Pv = (logR + lg2(ssum)) * LN2;
    if (lane == 0) sh[0] = Pv;
  }
  __syncthreads();

  const int* tg = tag + b * T_DIM;
  float sc = 0.f;
#pragma unroll
  for (int k = 0; k < 8; ++k) {
    int t = tid + k * 128;
    if (t >= 1) {
      int tc  = tg[t];
      int tm1 = tg[t - 1];
      int ls = 0;
      if (t >= 2) {
        int tm2 = tg[t - 2];
        ls = (tm2 == tm1) ? (tm1 < (L_DIM - 1) ? tm1 : (L_DIM - 1)) : 0;
      }
      sc += fb[((size_t)t * L_DIM + ls) * K_DIM + tc] + trans[tm1 * K_DIM + tc];
    }
  }
  if (tid == 0) sc += fb[tg[0]];
  for (int off = 32; off >= 1; off >>= 1) sc += __shfl_xor(sc, off, 64);
  if (lane == 0) sh[1 + wid] = sc;
  __syncthreads();
  if (tid == 0) out[b] = (sh[1] + sh[2]) - sh[0];
}

extern "C" void kernel_launch(void* const* d_in, const int* in_sizes, int n_in,
                              void* d_out, int out_size, void* d_ws, size_t ws_size,
                              hipStream_t stream) {
  const float* feat  = (const float*)d_in[0];
  const float* trans = (const float*)d_in[1];
  const int*   tag   = (const int*)d_in[2];
  float* out = (float*)d_out;

  fused_kernel<<<B_DIM, 128, 0, stream>>>(feat, trans, tag, out);
}

// Round 14
// 229.567 us; speedup vs baseline: 1.3436x; 1.3205x over previous
//
#include <hip/hip_runtime.h>

#define B_DIM 64
#define T_DIM 1024
#define LOG2E 1.44269504088896340736f
#define LN2   0.69314718055994530942f
#define EAB   32768   // byte offset of ea[64] region (after 8x4KB ef slots)

typedef float f32x2 __attribute__((ext_vector_type(2)));
typedef float f32x4 __attribute__((ext_vector_type(4)));

__device__ __forceinline__ float ex2(float x) { return __builtin_amdgcn_exp2f(x); }
__device__ __forceinline__ float lg2(float x) { return __builtin_amdgcn_logf(x); }
#define SB0()  __builtin_amdgcn_sched_barrier(0)
#define BARR() __builtin_amdgcn_s_barrier()

__device__ __forceinline__ unsigned int lds_addr(const float* p) {
  return (unsigned int)(size_t)(__attribute__((address_space(3))) const float*)p;
}
template<int IMM> __device__ __forceinline__ f32x4 dsr128(unsigned int a) {
  f32x4 d; asm volatile("ds_read_b128 %0, %1 offset:%2" : "=v"(d) : "v"(a), "n"(IMM) : "memory"); return d;
}
template<int IMM> __device__ __forceinline__ void dsw32(unsigned int a, float v) {
  asm volatile("ds_write_b32 %0, %1 offset:%2" :: "v"(a), "v"(v), "n"(IMM) : "memory");
}
template<int IMM> __device__ __forceinline__ void dsw128(unsigned int a, f32x4 v) {
  asm volatile("ds_write_b128 %0, %1 offset:%2" :: "v"(a), "v"(v), "n"(IMM) : "memory");
}
template<int IMM> __device__ __forceinline__ void gld(float& d, const float* p) {
  asm volatile("global_load_dword %0, %1, off offset:%2" : "=v"(d) : "v"(p), "n"(IMM) : "memory");
}
template<int N> __device__ __forceinline__ void waitv() {
  if constexpr (N == 32)      asm volatile("s_waitcnt vmcnt(32)" ::: "memory");
  else                        asm volatile("s_waitcnt vmcnt(0)"  ::: "memory");
}
template<int N> __device__ __forceinline__ void waitl() {
  if constexpr (N == 12)      asm volatile("s_waitcnt lgkmcnt(12)" ::: "memory");
  else if constexpr (N == 8)  asm volatile("s_waitcnt lgkmcnt(8)"  ::: "memory");
  else if constexpr (N == 4)  asm volatile("s_waitcnt lgkmcnt(4)"  ::: "memory");
  else                        asm volatile("s_waitcnt lgkmcnt(0)"  ::: "memory");
}
__device__ __forceinline__ float rfl(float v) {
  return __uint_as_float(__builtin_amdgcn_readfirstlane(__float_as_uint(v)));
}

// ---------------- LDS layout (bytes) ----------------
// ef[8 slots][4 quads][64 lanes][16B]  @0      (slot = row & 7)
// ea[64] f32                           @32768
// ef quad addressing: byte = slot*4096 + quad*1024 + lane*16  (conflict-free)

// ================= w0: recursion step t, P = (t-1)&15 =================
// All state in registers: EA, EI[16] (g-ring), u, logR. Reads ef quads +
// ea broadcast quads; writes ea. Bit-identical arithmetic to round-8 kernel.
template<int P>
__device__ __forceinline__ void w0_step(
    float& EA, float& u, float& logR, float (&EI)[16],
    const f32x2 (&Ec)[32], unsigned int aU, unsigned int aE, unsigned int aW)
{
  constexpr bool REN   = ((P + 1) & 3) == 0;   // t % 4 == 0
  constexpr bool SAVEU = ((P + 1) & 3) == 3;   // t % 4 == 3
  constexpr int  EFs = ((P + 1) & 7) * 4096;   // slot t&7

  f32x4 e0 = dsr128<EFs + 0>(aE);
  f32x4 e1 = dsr128<EFs + 1024>(aE);
  f32x4 e2 = dsr128<EFs + 2048>(aE);
  f32x4 e3 = dsr128<EFs + 3072>(aE);
  f32x4 q0  = dsr128<EAB + 0>(aU),   q1  = dsr128<EAB + 16>(aU);
  f32x4 q2  = dsr128<EAB + 32>(aU),  q3  = dsr128<EAB + 48>(aU);
  f32x4 q4  = dsr128<EAB + 64>(aU),  q5  = dsr128<EAB + 80>(aU);
  f32x4 q6  = dsr128<EAB + 96>(aU),  q7  = dsr128<EAB + 112>(aU);
  f32x4 q8  = dsr128<EAB + 128>(aU), q9  = dsr128<EAB + 144>(aU);
  f32x4 q10 = dsr128<EAB + 160>(aU), q11 = dsr128<EAB + 176>(aU);
  f32x4 q12 = dsr128<EAB + 192>(aU), q13 = dsr128<EAB + 208>(aU);
  f32x4 q14 = dsr128<EAB + 224>(aU), q15 = dsr128<EAB + 240>(aU);

  f32x2 A0 = {0.f,0.f}, A1 = {0.f,0.f}, A2 = {0.f,0.f}, A3 = {0.f,0.f};
#define MV(j,q,Aa,Ab) { f32x2 _x={q.x,q.y},_y={q.z,q.w}; \
  Aa=__builtin_elementwise_fma(_x,Ec[2*(j)],Aa); Ab=__builtin_elementwise_fma(_y,Ec[2*(j)+1],Ab); }

  // outstanding: prev ea-write(<=1) + e0..e3 + q0..q15 = 21.
  waitl<12>(); SB0();                 // write + e0..e3 + q0..q3 retired
  MV(0,q0,A0,A1) MV(1,q1,A2,A3) MV(2,q2,A0,A1) MV(3,q3,A2,A3)

  float s = 1.0f;
  if (REN) {                          // exact power-of-two renorm
    unsigned int ub = __float_as_uint(u);
    int e = (int)((ub >> 23) & 255u);
    s = __uint_as_float((unsigned int)(254 - e) << 23);
    logR += (float)(e - 127);
#pragma unroll
    for (int i = 0; i < 16; ++i) EI[i] *= s;
  }
  float p0 = e0.y * EI[(P + 15) & 15];
  float p1 = e0.z * EI[(P + 14) & 15];
  float p2 = e0.w * EI[(P + 13) & 15];
  float p3 = e1.x * EI[(P + 12) & 15];
  p0 = fmaf(e1.y, EI[(P + 11) & 15], p0);
  p1 = fmaf(e1.z, EI[(P + 10) & 15], p1);
  p2 = fmaf(e1.w, EI[(P + 9)  & 15], p2);
  p3 = fmaf(e2.x, EI[(P + 8)  & 15], p3);
  p0 = fmaf(e2.y, EI[(P + 7)  & 15], p0);
  p1 = fmaf(e2.z, EI[(P + 6)  & 15], p1);
  p2 = fmaf(e2.w, EI[(P + 5)  & 15], p2);
  p3 = fmaf(e3.x, EI[(P + 4)  & 15], p3);
  p0 = fmaf(e3.y, EI[(P + 3)  & 15], p0);
  p1 = fmaf(e3.z, EI[(P + 2)  & 15], p1);
  p2 = fmaf(e3.w, EI[(P + 1)  & 15], p2);
  float partial = (p0 + p1) + (p2 + p3);

  waitl<8>(); SB0();
  MV(4,q4,A0,A1) MV(5,q5,A2,A3) MV(6,q6,A0,A1) MV(7,q7,A2,A3)
  waitl<4>(); SB0();
  MV(8,q8,A0,A1) MV(9,q9,A2,A3) MV(10,q10,A0,A1) MV(11,q11,A2,A3)
  waitl<0>(); SB0();
  MV(12,q12,A0,A1) MV(13,q13,A2,A3) MV(14,q14,A0,A1) MV(15,q15,A2,A3)
#undef MV
  f32x2 G = (A0 + A1) + (A2 + A3);
  float g = G.x + G.y;
  if (REN) g *= s;
  EI[P] = g;
  EA = fmaf(e0.x, g, partial);
  dsw32<EAB>(aW, EA);                 // broadcast for next step (same wave)
  if (SAVEU) u = rfl(EA);
}

// ================= w1: ef producer =================
__device__ __forceinline__ void issue_row(float (&b)[16], const float*& pgl, int& nir) {
  gld<0>(b[0], pgl);     gld<256>(b[1], pgl);   gld<512>(b[2], pgl);   gld<768>(b[3], pgl);
  gld<1024>(b[4], pgl);  gld<1280>(b[5], pgl);  gld<1536>(b[6], pgl);  gld<1792>(b[7], pgl);
  gld<2048>(b[8], pgl);  gld<2304>(b[9], pgl);  gld<2560>(b[10], pgl); gld<2816>(b[11], pgl);
  gld<3072>(b[12], pgl); gld<3328>(b[13], pgl); gld<3584>(b[14], pgl); gld<3840>(b[15], pgl);
  if (nir < 1023) pgl += T_DIM;   // clamp: rows >=1024 re-read row 1023 (unused)
  ++nir;
}
template<int SLOT>
__device__ __forceinline__ void expwrite(const float (&bC)[16], unsigned int aEw) {
  float x0  = ex2(bC[0]  * LOG2E), x1  = ex2(bC[1]  * LOG2E);
  float x2  = ex2(bC[2]  * LOG2E), x3  = ex2(bC[3]  * LOG2E);
  float x4  = ex2(bC[4]  * LOG2E), x5  = ex2(bC[5]  * LOG2E);
  float x6  = ex2(bC[6]  * LOG2E), x7  = ex2(bC[7]  * LOG2E);
  float x8  = ex2(bC[8]  * LOG2E), x9  = ex2(bC[9]  * LOG2E);
  float x10 = ex2(bC[10] * LOG2E), x11 = ex2(bC[11] * LOG2E);
  float x12 = ex2(bC[12] * LOG2E), x13 = ex2(bC[13] * LOG2E);
  float x14 = ex2(bC[14] * LOG2E), x15 = ex2(bC[15] * LOG2E);
  f32x4 v0 = {x0,x1,x2,x3}, v1 = {x4,x5,x6,x7};
  f32x4 v2 = {x8,x9,x10,x11}, v3 = {x12,x13,x14,x15};
  dsw128<SLOT*4096 + 0>(aEw, v0);
  dsw128<SLOT*4096 + 1024>(aEw, v1);
  dsw128<SLOT*4096 + 2048>(aEw, v2);
  dsw128<SLOT*4096 + 3072>(aEw, v3);
}
template<int SLOT>
__device__ __forceinline__ void w1_row(const float*& pgl, int& nir,
    float (&bI)[16], const float (&bC)[16], unsigned int aEw) {
  issue_row(bI, pgl, nir);            // row r+2 -> bI (2-ahead pipeline)
  waitv<32>(); SB0();                 // rows r+1,r+2 in flight -> row r retired
  expwrite<SLOT>(bC, aEw);            // bC holds row r
}
template<int WOFF>  // first slot of this window: 5 (even windows) or 1 (odd)
__device__ __forceinline__ void w1_window(const float*& pgl, int& nir,
    float (&b0)[16], float (&b1)[16], float (&b2)[16], float (&b3)[16],
    unsigned int aEw) {
  w1_row<(WOFF + 0) & 7>(pgl, nir, b3, b1, aEw);
  w1_row<(WOFF + 1) & 7>(pgl, nir, b0, b2, aEw);
  w1_row<(WOFF + 2) & 7>(pgl, nir, b1, b3, aEw);
  w1_row<(WOFF + 3) & 7>(pgl, nir, b2, b0, aEw);
  waitl<0>(); SB0();                  // drain ef writes before barrier
}

#define W0X4(a,b,c,d) { w0_step<a>(EA,u,logR,EI,Ec,aU,aE,aW); w0_step<b>(EA,u,logR,EI,Ec,aU,aE,aW); \
                        w0_step<c>(EA,u,logR,EI,Ec,aU,aE,aW); w0_step<d>(EA,u,logR,EI,Ec,aU,aE,aW); }

__global__ __launch_bounds__(128, 1) void fused_kernel(
    const float* __restrict__ feat, const float* __restrict__ trans,
    const int* __restrict__ tag, float* __restrict__ out)
{
  const int b = blockIdx.x;
  const int tid = threadIdx.x;
  const int lane = tid & 63;
  const int wid = tid >> 6;
  const float* fb = feat + (size_t)b * T_DIM * 1024;   // 1024 floats per row

  __shared__ __align__(16) float sh[8448];   // 32KB ef + 256B ea + pad

  unsigned int aU = lds_addr(sh);             // uniform base (ea quads)
  unsigned int aE = lds_addr(sh) + lane * 16; // ef quads / writes (b128 lane-contig)
  unsigned int aW = lds_addr(sh) + lane * 4;  // ea write
  asm volatile("" : "+v"(aU), "+v"(aE), "+v"(aW));

  f32x2 Ec[32];
  float EI[16];
  float EA = 0.f, u = 1.0f, logR = 0.0f;
  float b0[16], b1[16], b2[16], b3[16];
  const float* pgl = fb + T_DIM + lane;       // row 1, this lane
  int nir = 1;

  // ---------------- prologue ----------------
  if (wid == 0) {
#pragma unroll
    for (int k = 0; k < 32; ++k) {
      f32x2 t2 = {ex2(trans[(2 * k) * 64 + lane] * LOG2E),
                  ex2(trans[(2 * k + 1) * 64 + lane] * LOG2E)};
      Ec[k] = t2;
    }
#pragma unroll
    for (int k = 0; k < 32; ++k) asm volatile("" : "+v"(Ec[k]));
#pragma unroll
    for (int i = 0; i < 16; ++i) EI[i] = 0.f;
    EA = ex2(fb[lane] * LOG2E);               // alpha_0 (exp domain)
    dsw32<EAB>(aW, EA);
  } else {
    issue_row(b1, pgl, nir);  issue_row(b2, pgl, nir);   // rows 1,2
    issue_row(b3, pgl, nir);  issue_row(b0, pgl, nir);   // rows 3,4
    waitv<0>(); SB0();
    expwrite<1>(b1, aE); expwrite<2>(b2, aE);
    expwrite<3>(b3, aE); expwrite<4>(b0, aE);
    issue_row(b1, pgl, nir);  issue_row(b2, pgl, nir);   // rows 5,6 in flight
    waitl<0>(); SB0();
  }
  SB0(); BARR();

  // ---------------- main: 63 chunks x 4 windows (steps t = 1..1008) --------
#pragma unroll 1
  for (int c = 0; c < 63; ++c) {
    if (wid == 0) W0X4(0,1,2,3)   else w1_window<5>(pgl, nir, b0,b1,b2,b3, aE);
    SB0(); BARR();
    if (wid == 0) W0X4(4,5,6,7)   else w1_window<1>(pgl, nir, b0,b1,b2,b3, aE);
    SB0(); BARR();
    if (wid == 0) W0X4(8,9,10,11) else w1_window<5>(pgl, nir, b0,b1,b2,b3, aE);
    SB0(); BARR();
    if (wid == 0) W0X4(12,13,14,15) else w1_window<1>(pgl, nir, b0,b1,b2,b3, aE);
    SB0(); BARR();
  }
  // windows 252..254 (steps 1009..1020), then 3-step tail (t = 1021..1023)
  if (wid == 0) W0X4(0,1,2,3)   else w1_window<5>(pgl, nir, b0,b1,b2,b3, aE);
  SB0(); BARR();
  if (wid == 0) W0X4(4,5,6,7)   else w1_window<1>(pgl, nir, b0,b1,b2,b3, aE);
  SB0(); BARR();
  if (wid == 0) W0X4(8,9,10,11) else w1_window<5>(pgl, nir, b0,b1,b2,b3, aE);
  SB0(); BARR();
  if (wid == 0) {
    w0_step<12>(EA,u,logR,EI,Ec,aU,aE,aW);
    w0_step<13>(EA,u,logR,EI,Ec,aU,aE,aW);
    w0_step<14>(EA,u,logR,EI,Ec,aU,aE,aW);
  }
  SB0();

  // ---------------- epilogue: partition + score ----------------
  if (wid == 0) {
    float ssum = EA;
    for (int off = 32; off >= 1; off >>= 1) ssum += __shfl_xor(ssum, off, 64);
    float Pv = (logR + lg2(ssum)) * LN2;
    if (lane == 0) sh[0] = Pv;
  }
  __syncthreads();

  const int* tg = tag + b * T_DIM;
  float sc = 0.f;
#pragma unroll
  for (int k = 0; k < 8; ++k) {
    int t = tid + k * 128;
    if (t >= 1) {
      int tc  = tg[t];
      int tm1 = tg[t - 1];
      int ls = 0;
      if (t >= 2) {
        int tm2 = tg[t - 2];
        ls = (tm2 == tm1) ? (tm1 < 15 ? tm1 : 15) : 0;
      }
      sc += fb[((size_t)t * 16 + ls) * 64 + tc] + trans[tm1 * 64 + tc];
    }
  }
  if (tid == 0) sc += fb[tg[0]];
  for (int off = 32; off >= 1; off >>= 1) sc += __shfl_xor(sc, off, 64);
  if (lane == 0) sh[1 + wid] = sc;
  __syncthreads();
  if (tid == 0) out[b] = (sh[1] + sh[2]) - sh[0];
}

extern "C" void kernel_launch(void* const* d_in, const int* in_sizes, int n_in,
                              void* d_out, int out_size, void* d_ws, size_t ws_size,
                              hipStream_t stream) {
  const float* feat  = (const float*)d_in[0];
  const float* trans = (const float*)d_in[1];
  const int*   tag   = (const int*)d_in[2];
  float* out = (float*)d_out;

  fused_kernel<<<B_DIM, 128, 0, stream>>>(feat, trans, tag, out);
}